// Round 1
// baseline (5639.930 us; speedup 1.0000x reference)
//
#include <hip/hip_runtime.h>
#include <cstdint>
#include <cstddef>

#define B_  64
#define SE_ 128
#define T_  64
#define S_  1024
#define D_  1024
#define V_  32000

__device__ __forceinline__ float sigmoidf_(float x){ return 1.0f/(1.0f+__expf(-x)); }

__device__ __forceinline__ float waveRedSum(float v){
  #pragma unroll
  for (int off = 32; off; off >>= 1) v += __shfl_down(v, off, 64);
  return v;
}

// v[s'] = sum_s ayi_w[s',s] * aw_w[s]
__global__ void k_attnvec(const float* __restrict__ ayi_w, const float* __restrict__ aw_w,
                          float* __restrict__ v){
  int wave = (blockIdx.x * blockDim.x + threadIdx.x) >> 6;
  int lane = threadIdx.x & 63;
  if (wave >= S_) return;
  const float* row = ayi_w + (size_t)wave * S_;
  float acc = 0.f;
  #pragma unroll 4
  for (int s = lane; s < S_; s += 64) acc += row[s] * aw_w[s];
  acc = waveRedSum(acc);
  if (lane == 0) v[wave] = acc;
}

// scores[b*SE+e] = yts[b,e,:] . v
__global__ void k_scores(const float* __restrict__ yts, const float* __restrict__ v,
                         float* __restrict__ scores){
  int wave = (blockIdx.x * blockDim.x + threadIdx.x) >> 6; // 0..8191
  int lane = threadIdx.x & 63;
  const float* row = yts + (size_t)wave * S_;
  float acc = 0.f;
  #pragma unroll 4
  for (int s = lane; s < S_; s += 64) acc += row[s] * v[s];
  acc = waveRedSum(acc);
  if (lane == 0) scores[wave] = acc;
}

// per-b softmax over SE=128; write attnw and replicate into out attns [B][T][SE]
__global__ void k_attn(const float* __restrict__ scores, float* __restrict__ attnw,
                       float* __restrict__ outAttn){
  int b = blockIdx.x;
  int e = threadIdx.x; // 128 threads
  __shared__ float sm[128];
  float x = scores[b*SE_ + e];
  sm[e] = x; __syncthreads();
  #pragma unroll
  for (int off = 64; off; off >>= 1){
    if (e < off) sm[e] = fmaxf(sm[e], sm[e+off]);
    __syncthreads();
  }
  float m = sm[0]; __syncthreads();
  float p = __expf(x - m);
  sm[e] = p; __syncthreads();
  #pragma unroll
  for (int off = 64; off; off >>= 1){
    if (e < off) sm[e] += sm[e+off];
    __syncthreads();
  }
  float a = p / sm[0];
  attnw[b*SE_ + e] = a;
  float* dst = outAttn + (size_t)b * T_ * SE_ + e;
  #pragma unroll 4
  for (int t = 0; t < T_; ++t) dst[t*SE_] = a;
}

// ctx[b,s] = sum_e attnw[b,e] * yts[b,e,s]
__global__ void k_ctx(const float* __restrict__ yts, const float* __restrict__ attnw,
                      float* __restrict__ ctx){
  int idx = blockIdx.x * blockDim.x + threadIdx.x; // 65536
  int b = idx >> 10, s = idx & (S_-1);
  const float* base = yts + (size_t)b * SE_ * S_ + s;
  const float* a = attnw + b * SE_;
  float acc = 0.f;
  #pragma unroll 8
  for (int e = 0; e < SE_; ++e) acc += a[e] * base[(size_t)e * S_];
  ctx[idx] = acc;
}

// pack 4 [1024,1024] gate matrices into [1024][4096]
__global__ void k_pack4(const float* __restrict__ p0, const float* __restrict__ p1,
                        const float* __restrict__ p2, const float* __restrict__ p3,
                        float* __restrict__ dst){
  int idx = blockIdx.x * blockDim.x + threadIdx.x; // 4M
  int k = idx >> 12, col = idx & 4095, g = col >> 10, s = col & 1023;
  const float* p = (g==0) ? p0 : (g==1) ? p1 : (g==2) ? p2 : p3;
  dst[idx] = p[k*S_ + s];
}

__global__ void k_packbias(const float* __restrict__ wb0, const float* __restrict__ wb1,
                           const float* __restrict__ wb2, const float* __restrict__ wb3,
                           const float* __restrict__ ub0, const float* __restrict__ ub1,
                           const float* __restrict__ ub2, const float* __restrict__ ub3,
                           float* __restrict__ dst){
  int col = blockIdx.x * blockDim.x + threadIdx.x; // 4096
  int g = col >> 10, s = col & 1023;
  const float* wb = (g==0) ? wb0 : (g==1) ? wb1 : (g==2) ? wb2 : wb3;
  const float* ub = (g==0) ? ub0 : (g==1) ? ub1 : (g==2) ? ub2 : ub3;
  dst[col] = wb[s] + ub[s];
}

// Generic fp32 tiled GEMM: C[M,N] (+= over split-K partials) = A[M,K] @ B[K,N] (+ bias)
// BM=BN=64, BK=16, 256 threads, 4x4 micro-tile.
// GATHER: A row r comes from emb[tgt[(r&63)*64 + (r>>6)]]
// REMAP:  C row r is stored at row ((r&63)<<6) + (r>>6)   (t*B+b -> b*T+t)
// blockIdx.z selects K-chunk; partial written to C + z*M*N.
template<bool GATHER, bool REMAP>
__global__ __launch_bounds__(256) void k_gemm(
    const float* __restrict__ A, const float* __restrict__ Bm,
    const float* __restrict__ bias, float* __restrict__ C,
    const int* __restrict__ tgt, int M, int N,
    int lda, int ldb, int kChunk)
{
  __shared__ float As[16][68]; // transposed: As[k][m]
  __shared__ float Bs[16][68];
  const int tid = threadIdx.x;
  const int tx = tid & 15, ty = tid >> 4;
  const int n0 = blockIdx.x * 64, m0 = blockIdx.y * 64;
  const int kBeg = blockIdx.z * kChunk;
  float* Cp = C + (size_t)blockIdx.z * ((size_t)M * (size_t)N);

  const int arow = tid >> 2;        // 0..63
  const int akk  = (tid & 3) << 2;  // 0,4,8,12
  const float* Abase;
  if (GATHER) {
    int r = m0 + arow;
    int token = tgt[((r & 63) << 6) + (r >> 6)];
    Abase = A + (size_t)token * lda + akk;
  } else {
    Abase = A + (size_t)(m0 + arow) * lda + akk;
  }
  const int bcol = (tid & 15) << 2; // 0..60
  const int bkk  = tid >> 4;        // 0..15
  const float* Bbase = Bm + (size_t)bkk * ldb + n0 + bcol;

  float acc[4][4];
  #pragma unroll
  for (int i = 0; i < 4; ++i)
    #pragma unroll
    for (int j = 0; j < 4; ++j) acc[i][j] = 0.f;

  for (int kt = 0; kt < kChunk; kt += 16) {
    float4 av = *(const float4*)(Abase + kBeg + kt);
    float4 bv = *(const float4*)(Bbase + (size_t)(kBeg + kt) * ldb);
    As[akk+0][arow] = av.x;
    As[akk+1][arow] = av.y;
    As[akk+2][arow] = av.z;
    As[akk+3][arow] = av.w;
    *(float4*)&Bs[bkk][bcol] = bv;
    __syncthreads();
    #pragma unroll
    for (int k = 0; k < 16; ++k) {
      float4 a4 = *(const float4*)&As[k][ty << 2];
      float4 b4 = *(const float4*)&Bs[k][tx << 2];
      acc[0][0] += a4.x*b4.x; acc[0][1] += a4.x*b4.y; acc[0][2] += a4.x*b4.z; acc[0][3] += a4.x*b4.w;
      acc[1][0] += a4.y*b4.x; acc[1][1] += a4.y*b4.y; acc[1][2] += a4.y*b4.z; acc[1][3] += a4.y*b4.w;
      acc[2][0] += a4.z*b4.x; acc[2][1] += a4.z*b4.y; acc[2][2] += a4.z*b4.z; acc[2][3] += a4.z*b4.w;
      acc[3][0] += a4.w*b4.x; acc[3][1] += a4.w*b4.y; acc[3][2] += a4.w*b4.z; acc[3][3] += a4.w*b4.w;
    }
    __syncthreads();
  }

  #pragma unroll
  for (int i = 0; i < 4; ++i) {
    int r = m0 + (ty << 2) + i;
    size_t orow = REMAP ? (size_t)(((r & 63) << 6) + (r >> 6)) : (size_t)r;
    float* crow = Cp + orow * (size_t)N + n0 + (tx << 2);
    #pragma unroll
    for (int j = 0; j < 4; ++j) {
      float cv = acc[i][j];
      if (bias) cv += bias[n0 + (tx << 2) + j];
      crow[j] = cv;
    }
  }
}

// combine split-K gate partials + pre, apply LSTM cell pointwise, write H[t]
__global__ void k_lstm_point(const float* __restrict__ gatesP, const float* __restrict__ pre_t,
                             const float* __restrict__ ctx, float* __restrict__ Hout){
  int idx = blockIdx.x * blockDim.x + threadIdx.x; // 65536
  int b = idx >> 10, s = idx & 1023;
  int base = (b << 12) + s;
  float fp = pre_t[base], ip = pre_t[base+1024], op = pre_t[base+2048], cp = pre_t[base+3072];
  #pragma unroll
  for (int c = 0; c < 8; ++c) {
    const float* g = gatesP + (size_t)c * (B_*4096) + base;
    fp += g[0]; ip += g[1024]; op += g[2048]; cp += g[3072];
  }
  float ft = sigmoidf_(fp), it = sigmoidf_(ip), ot = sigmoidf_(op);
  float cb = tanhf(cp);
  float ct = ft * ctx[idx] + it * cb;
  Hout[idx] = ot * tanhf(ct);
}

// in-place row softmax over V=32000, one block per row
__global__ __launch_bounds__(256) void k_softmaxV(float* __restrict__ out){
  int row = blockIdx.x; // 0..4095
  float* p = out + (size_t)row * V_;
  int tid = threadIdx.x;
  float m = -1e30f, ssum = 0.f;
  for (int i = tid; i < V_; i += 256) {
    float x = p[i];
    float mn = fmaxf(m, x);
    ssum = ssum * __expf(m - mn) + __expf(x - mn);
    m = mn;
  }
  __shared__ float ms[256], ss[256];
  ms[tid] = m; ss[tid] = ssum; __syncthreads();
  #pragma unroll
  for (int off = 128; off; off >>= 1) {
    if (tid < off) {
      float m2 = fmaxf(ms[tid], ms[tid+off]);
      ss[tid] = ss[tid]*__expf(ms[tid]-m2) + ss[tid+off]*__expf(ms[tid+off]-m2);
      ms[tid] = m2;
    }
    __syncthreads();
  }
  float M = ms[0];
  float inv = 1.0f / ss[0];
  for (int i = tid; i < V_; i += 256) {
    p[i] = __expf(p[i] - M) * inv;
  }
}

extern "C" void kernel_launch(void* const* d_in, const int* in_sizes, int n_in,
                              void* d_out, int out_size, void* d_ws, size_t ws_size,
                              hipStream_t stream){
  const float* yts   = (const float*)d_in[0];
  const float* enc_h = (const float*)d_in[1];
  const int*   tgt   = (const int*)d_in[2];
  const float* emb   = (const float*)d_in[3];
  // d_in[4] asi_w, d_in[5] asi_b, d_in[7] ayi_b, d_in[9] aw_b: provably unused
  const float* ayi_w = (const float*)d_in[6];
  const float* aw_w  = (const float*)d_in[8];
  const float* wf_w = (const float*)d_in[10]; const float* wf_b = (const float*)d_in[11];
  const float* uf_w = (const float*)d_in[12]; const float* uf_b = (const float*)d_in[13];
  const float* wi_w = (const float*)d_in[14]; const float* wi_b = (const float*)d_in[15];
  const float* ui_w = (const float*)d_in[16]; const float* ui_b = (const float*)d_in[17];
  const float* wo_w = (const float*)d_in[18]; const float* wo_b = (const float*)d_in[19];
  const float* uo_w = (const float*)d_in[20]; const float* uo_b = (const float*)d_in[21];
  const float* wc_w = (const float*)d_in[22]; const float* wc_b = (const float*)d_in[23];
  const float* uc_w = (const float*)d_in[24]; const float* uc_b = (const float*)d_in[25];
  const float* xh_w = (const float*)d_in[26]; const float* xh_b = (const float*)d_in[27];
  const float* cls_w= (const float*)d_in[28]; const float* cls_b= (const float*)d_in[29];

  float* out = (float*)d_out;
  float* outAttn = out + (size_t)B_ * T_ * V_;

  float* ws = (float*)d_ws;
  size_t off = 0;
  float* Wcat  = ws + off; off += (size_t)S_ * 4096;       // 4M
  float* Ucat  = ws + off; off += (size_t)D_ * 4096;       // 4M
  float* biasU = ws + off; off += 4096;
  float* vvec  = ws + off; off += S_;
  float* scores= ws + off; off += B_ * SE_;
  float* attnw = ws + off; off += B_ * SE_;
  float* ctx   = ws + off; off += B_ * S_;
  float* pre   = ws + off; off += (size_t)T_ * B_ * 4096;  // 16.7M
  float* H     = ws + off; off += (size_t)T_ * B_ * S_;    // 4M
  float* Z     = ws + off; off += (size_t)T_ * B_ * D_;    // 4M
  float* gatesP= ws + off; off += (size_t)8 * B_ * 4096;   // 2M
  if (ws_size < off * sizeof(float)) return; // insufficient scratch: bail cleanly

  // ---- prep (parallel, order-independent except noted) ----
  k_pack4<<<16384, 256, 0, stream>>>(wf_w, wi_w, wo_w, wc_w, Wcat);
  k_pack4<<<16384, 256, 0, stream>>>(uf_w, ui_w, uo_w, uc_w, Ucat);
  k_packbias<<<16, 256, 0, stream>>>(wf_b, wi_b, wo_b, wc_b, uf_b, ui_b, uo_b, uc_b, biasU);
  k_attnvec<<<256, 256, 0, stream>>>(ayi_w, aw_w, vvec);
  k_scores<<<2048, 256, 0, stream>>>(yts, vvec, scores);
  k_attn<<<64, 128, 0, stream>>>(scores, attnw, outAttn);
  k_ctx<<<256, 256, 0, stream>>>(yts, attnw, ctx);

  // pre[t*B+b, :] = emb[tgt[b,t]] @ Ucat + biasU   (M=4096,N=4096,K=1024)
  k_gemm<true, false><<<dim3(64, 64, 1), 256, 0, stream>>>(
      emb, Ucat, biasU, pre, tgt, T_*B_, 4096, D_, 4096, 1024);

  // ---- sequential LSTM recurrence ----
  for (int t = 0; t < T_; ++t) {
    const float* st = (t == 0) ? enc_h : (H + (size_t)(t-1) * B_ * S_);
    // gates partials: [8][64][4096], split-K=8 (kChunk=128)
    k_gemm<false, false><<<dim3(64, 1, 8), 256, 0, stream>>>(
        st, Wcat, nullptr, gatesP, nullptr, B_, 4096, S_, 4096, 128);
    k_lstm_point<<<256, 256, 0, stream>>>(
        gatesP, pre + (size_t)t * B_ * 4096, ctx, H + (size_t)t * B_ * S_);
  }

  // ---- batched epilogue over all T ----
  // Z = H @ xh_w + xh_b   (M=4096,N=1024,K=1024)
  k_gemm<false, false><<<dim3(16, 64, 1), 256, 0, stream>>>(
      H, xh_w, xh_b, Z, nullptr, T_*B_, D_, S_, D_, S_);
  // logits -> out (remapped rows t*B+b -> b*T+t)  (M=4096,N=32000,K=1024)
  k_gemm<false, true><<<dim3(500, 64, 1), 256, 0, stream>>>(
      Z, cls_w, cls_b, out, nullptr, T_*B_, V_, D_, V_, D_);
  // softmax in place over V
  k_softmaxV<<<4096, 256, 0, stream>>>(out);
}

// Round 2
// 2997.330 us; speedup vs baseline: 1.8817x; 1.8817x over previous
//
#include <hip/hip_runtime.h>
#include <cstdint>
#include <cstddef>

#define B_  64
#define SE_ 128
#define T_  64
#define S_  1024
#define D_  1024
#define V_  32000

typedef __attribute__((ext_vector_type(8))) short bhalf8;
typedef __attribute__((ext_vector_type(4))) float floatx4;

__device__ __forceinline__ float sigmoidf_(float x){ return 1.0f/(1.0f+__expf(-x)); }

__device__ __forceinline__ ushort f2bf(float f){
  uint32_t u = __float_as_uint(f);
  uint32_t r = (u + 0x7fffu + ((u >> 16) & 1u)) >> 16;
  return (ushort)r;
}
__device__ __forceinline__ float bf2f(ushort h){ return __uint_as_float(((uint32_t)h) << 16); }

__device__ __forceinline__ void glds16(const ushort* g, ushort* l){
  __builtin_amdgcn_global_load_lds((const __attribute__((address_space(1))) void*)g,
                                   (__attribute__((address_space(3))) void*)l, 16, 0, 0);
}

__device__ __forceinline__ float waveRedSum(float v){
  #pragma unroll
  for (int off = 32; off; off >>= 1) v += __shfl_down(v, off, 64);
  return v;
}

// ---------------- attention path (fp32, small) ----------------

__global__ void k_attnvec(const float* __restrict__ ayi_w, const float* __restrict__ aw_w,
                          float* __restrict__ v){
  int wave = (blockIdx.x * blockDim.x + threadIdx.x) >> 6;
  int lane = threadIdx.x & 63;
  if (wave >= S_) return;
  const float* row = ayi_w + (size_t)wave * S_;
  float acc = 0.f;
  #pragma unroll 4
  for (int s = lane; s < S_; s += 64) acc += row[s] * aw_w[s];
  acc = waveRedSum(acc);
  if (lane == 0) v[wave] = acc;
}

__global__ void k_scores(const float* __restrict__ yts, const float* __restrict__ v,
                         float* __restrict__ scores){
  int wave = (blockIdx.x * blockDim.x + threadIdx.x) >> 6;
  int lane = threadIdx.x & 63;
  const float* row = yts + (size_t)wave * S_;
  float acc = 0.f;
  #pragma unroll 4
  for (int s = lane; s < S_; s += 64) acc += row[s] * v[s];
  acc = waveRedSum(acc);
  if (lane == 0) scores[wave] = acc;
}

__global__ void k_attn(const float* __restrict__ scores, float* __restrict__ attnw,
                       float* __restrict__ outAttn){
  int b = blockIdx.x;
  int e = threadIdx.x;
  __shared__ float sm[128];
  float x = scores[b*SE_ + e];
  sm[e] = x; __syncthreads();
  #pragma unroll
  for (int off = 64; off; off >>= 1){
    if (e < off) sm[e] = fmaxf(sm[e], sm[e+off]);
    __syncthreads();
  }
  float m = sm[0]; __syncthreads();
  float p = __expf(x - m);
  sm[e] = p; __syncthreads();
  #pragma unroll
  for (int off = 64; off; off >>= 1){
    if (e < off) sm[e] += sm[e+off];
    __syncthreads();
  }
  float a = p / sm[0];
  attnw[b*SE_ + e] = a;
  float* dst = outAttn + (size_t)b * T_ * SE_ + e;
  #pragma unroll 4
  for (int t = 0; t < T_; ++t) dst[t*SE_] = a;
}

__global__ void k_ctx(const float* __restrict__ yts, const float* __restrict__ attnw,
                      float* __restrict__ ctx){
  int idx = blockIdx.x * blockDim.x + threadIdx.x;
  int b = idx >> 10, s = idx & (S_-1);
  const float* base = yts + (size_t)b * SE_ * S_ + s;
  const float* a = attnw + b * SE_;
  float acc = 0.f;
  #pragma unroll 8
  for (int e = 0; e < SE_; ++e) acc += a[e] * base[(size_t)e * S_];
  ctx[idx] = acc;
}

// ---------------- conversion / packing ----------------

// src[K][N] f32 -> dst[N][K] bf16 (transpose + convert), block (32,8), grid (N/32, K/32)
__global__ void k_transcvt(const float* __restrict__ src, ushort* __restrict__ dst,
                           int K, int N){
  __shared__ float t[32][33];
  int n0 = blockIdx.x * 32, k0 = blockIdx.y * 32;
  for (int r = threadIdx.y; r < 32; r += 8)
    t[r][threadIdx.x] = src[(size_t)(k0 + r) * N + n0 + threadIdx.x];
  __syncthreads();
  for (int r = threadIdx.y; r < 32; r += 8)
    dst[(size_t)(n0 + r) * K + k0 + threadIdx.x] = f2bf(t[threadIdx.x][r]);
}

__global__ void k_cvt(const float* __restrict__ src, ushort* __restrict__ dst, int n4){
  int i = blockIdx.x * blockDim.x + threadIdx.x;
  if (i >= n4) return;
  float4 v = ((const float4*)src)[i];
  ushort4 o; o.x = f2bf(v.x); o.y = f2bf(v.y); o.z = f2bf(v.z); o.w = f2bf(v.w);
  ((ushort4*)dst)[i] = o;
}

// Xb[r][k] = bf16(emb[tgt[b,t]][k]), r = t*64+b
__global__ void k_gathercvt(const float* __restrict__ emb, const int* __restrict__ tgt,
                            ushort* __restrict__ Xb){
  int r = blockIdx.x;
  int token = tgt[((r & 63) << 6) + (r >> 6)];
  const float4* src = (const float4*)(emb + (size_t)token * D_);
  ushort* dst = Xb + (size_t)r * D_;
  int i = threadIdx.x; // 0..255
  float4 v = src[i];
  ushort4 o; o.x = f2bf(v.x); o.y = f2bf(v.y); o.z = f2bf(v.z); o.w = f2bf(v.w);
  ((ushort4*)dst)[i] = o;
}

__global__ void k_packbias(const float* __restrict__ wb0, const float* __restrict__ wb1,
                           const float* __restrict__ wb2, const float* __restrict__ wb3,
                           const float* __restrict__ ub0, const float* __restrict__ ub1,
                           const float* __restrict__ ub2, const float* __restrict__ ub3,
                           float* __restrict__ dst){
  int col = blockIdx.x * blockDim.x + threadIdx.x;
  int g = col >> 10, s = col & 1023;
  const float* wb = (g==0) ? wb0 : (g==1) ? wb1 : (g==2) ? wb2 : wb3;
  const float* ub = (g==0) ? ub0 : (g==1) ? ub1 : (g==2) ? ub2 : ub3;
  dst[col] = wb[s] + ub[s];
}

// ---------------- bf16 MFMA GEMM (m97 structure) ----------------
// C[M][N] = A[M][K=1024] * BT[N][K=1024]^T (+ bias[N])
// 128x128 tile, BK=32, 4 waves (2x2), each wave 64x64 = 4x4 frags of 16x16x32.
// OUT_MODE: 0 = f32, 1 = f32 with row remap (t*64+b -> b*64+t), 2 = bf16
template<int OUT_MODE>
__global__ __launch_bounds__(256) void k_mfma_gemm(
    const ushort* __restrict__ A, const ushort* __restrict__ BT,
    const float* __restrict__ bias, void* __restrict__ C, int M, int N)
{
  __shared__ ushort As[128*32];
  __shared__ ushort Bs[128*32];
  const int tid = threadIdx.x;
  const int lane = tid & 63, w = tid >> 6;
  const int m0 = blockIdx.y * 128, n0 = blockIdx.x * 128;
  const int wr = (w >> 1) * 64, wc = (w & 1) * 64;

  // staging: wave w stages A chunks {2w,2w+1}, B chunks {2w,2w+1}; chunk = 16 rows x 32 k
  const int cr = (lane >> 2);           // row within chunk
  const int ck = (lane & 3) * 8;        // k elem offset
  const ushort* gA0 = A  + (size_t)(m0 + (2*w)*16   + cr) * 1024 + ck;
  const ushort* gA1 = A  + (size_t)(m0 + (2*w+1)*16 + cr) * 1024 + ck;
  const ushort* gB0 = BT + (size_t)(n0 + (2*w)*16   + cr) * 1024 + ck;
  const ushort* gB1 = BT + (size_t)(n0 + (2*w+1)*16 + cr) * 1024 + ck;
  ushort* lA0 = As + (2*w)*512;   ushort* lA1 = As + (2*w+1)*512;
  ushort* lB0 = Bs + (2*w)*512;   ushort* lB1 = Bs + (2*w+1)*512;

  floatx4 acc[4][4] = {};

  for (int kt = 0; kt < 1024; kt += 32) {
    glds16(gA0 + kt, lA0); glds16(gA1 + kt, lA1);
    glds16(gB0 + kt, lB0); glds16(gB1 + kt, lB1);
    __syncthreads();
    bhalf8 a[4], b[4];
    #pragma unroll
    for (int f = 0; f < 4; ++f) {
      a[f] = *(const bhalf8*)&As[(wr + f*16 + (lane & 15)) * 32 + (lane >> 4) * 8];
      b[f] = *(const bhalf8*)&Bs[(wc + f*16 + (lane & 15)) * 32 + (lane >> 4) * 8];
    }
    #pragma unroll
    for (int i = 0; i < 4; ++i)
      #pragma unroll
      for (int j = 0; j < 4; ++j)
        acc[i][j] = __builtin_amdgcn_mfma_f32_16x16x32_bf16(a[i], b[j], acc[i][j], 0, 0, 0);
    __syncthreads();
  }

  const int crow = (lane >> 4) * 4, ccol = lane & 15;
  #pragma unroll
  for (int i = 0; i < 4; ++i) {
    #pragma unroll
    for (int j = 0; j < 4; ++j) {
      int row = m0 + wr + i*16 + crow;
      int col = n0 + wc + j*16 + ccol;
      float bv = bias ? bias[col] : 0.f;
      #pragma unroll
      for (int r = 0; r < 4; ++r) {
        float v = acc[i][j][r] + bv;
        if (OUT_MODE == 0) {
          ((float*)C)[(size_t)(row + r) * N + col] = v;
        } else if (OUT_MODE == 1) {
          int rr = row + r;
          ((float*)C)[(size_t)(((rr & 63) << 6) + (rr >> 6)) * N + col] = v;
        } else {
          ((ushort*)C)[(size_t)(row + r) * N + col] = f2bf(v);
        }
      }
    }
  }
}

// ---------------- fused LSTM step ----------------
// 16 blocks (j = s-slice of 64 cols), 4 waves; wave w computes gate w's 64x64 tile
// via MFMA over K=1024, then block combines gates + pre + ctx pointwise -> Hout bf16.
__global__ __launch_bounds__(256) void k_step(
    const ushort* __restrict__ Hin,   // [64][1024] bf16
    const ushort* __restrict__ WT,    // [4096][1024] bf16 (rows: g*1024+s)
    const ushort* __restrict__ preb,  // [64][4096] bf16 (this step's slice)
    const float*  __restrict__ ctx,   // [64][1024] f32
    ushort* __restrict__ Hout)        // [64][1024] bf16
{
  __shared__ ushort As[64*32];
  __shared__ ushort Bs[4][64*32];
  __shared__ float gbuf[4][64][66];
  const int tid = threadIdx.x, lane = tid & 63, w = tid >> 6;
  const int j = blockIdx.x;

  const int cr = (lane >> 2);
  const int ck = (lane & 3) * 8;
  // A: 4 chunks of 16 rows; wave w stages chunk w
  const ushort* gA = Hin + (size_t)(w*16 + cr) * 1024 + ck;
  ushort* lA = As + w*512;
  // B: gate w panel rows = w*1024 + j*64 + (c*16 + cr)
  const ushort* gB = WT + (size_t)(w*1024 + j*64 + cr) * 1024 + ck;
  ushort* lB = Bs[w];

  floatx4 acc[4][4] = {};

  for (int kt = 0; kt < 1024; kt += 32) {
    glds16(gA + kt, lA);
    #pragma unroll
    for (int c = 0; c < 4; ++c)
      glds16(gB + (size_t)(c*16)*1024 + kt, lB + c*512);
    __syncthreads();
    bhalf8 a[4], b[4];
    #pragma unroll
    for (int f = 0; f < 4; ++f) {
      a[f] = *(const bhalf8*)&As[(f*16 + (lane & 15)) * 32 + (lane >> 4) * 8];
      b[f] = *(const bhalf8*)&Bs[w][(f*16 + (lane & 15)) * 32 + (lane >> 4) * 8];
    }
    #pragma unroll
    for (int i = 0; i < 4; ++i)
      #pragma unroll
      for (int jj = 0; jj < 4; ++jj)
        acc[i][jj] = __builtin_amdgcn_mfma_f32_16x16x32_bf16(a[i], b[jj], acc[i][jj], 0, 0, 0);
    __syncthreads();
  }

  const int crow = (lane >> 4) * 4, ccol = lane & 15;
  #pragma unroll
  for (int i = 0; i < 4; ++i)
    #pragma unroll
    for (int jj = 0; jj < 4; ++jj)
      #pragma unroll
      for (int r = 0; r < 4; ++r)
        gbuf[w][i*16 + crow + r][jj*16 + ccol] = acc[i][jj][r];
  __syncthreads();

  for (int idx = tid; idx < 4096; idx += 256) {
    int b = idx >> 6, sp = idx & 63;
    int s = j*64 + sp;
    float fp = gbuf[0][b][sp] + bf2f(preb[b*4096 + s]);
    float ip = gbuf[1][b][sp] + bf2f(preb[b*4096 + 1024 + s]);
    float op = gbuf[2][b][sp] + bf2f(preb[b*4096 + 2048 + s]);
    float cp = gbuf[3][b][sp] + bf2f(preb[b*4096 + 3072 + s]);
    float ft = sigmoidf_(fp), it = sigmoidf_(ip), ot = sigmoidf_(op);
    float cb = tanhf(cp);
    float ct = ft * ctx[b*1024 + s] + it * cb;
    Hout[(size_t)b*1024 + s] = f2bf(ot * tanhf(ct));
  }
}

// ---------------- row softmax over V=32000 ----------------
__global__ __launch_bounds__(256) void k_softmaxV(float* __restrict__ out){
  int row = blockIdx.x;
  float4* p = (float4*)(out + (size_t)row * V_);
  int tid = threadIdx.x;
  float m = -1e30f, ssum = 0.f;
  for (int i = tid; i < 8000; i += 256) {
    float4 v = p[i];
    float m4 = fmaxf(fmaxf(v.x, v.y), fmaxf(v.z, v.w));
    float mn = fmaxf(m, m4);
    ssum = ssum * __expf(m - mn)
         + __expf(v.x - mn) + __expf(v.y - mn) + __expf(v.z - mn) + __expf(v.w - mn);
    m = mn;
  }
  __shared__ float ms[256], ss[256];
  ms[tid] = m; ss[tid] = ssum; __syncthreads();
  #pragma unroll
  for (int off = 128; off; off >>= 1) {
    if (tid < off) {
      float m2 = fmaxf(ms[tid], ms[tid+off]);
      ss[tid] = ss[tid]*__expf(ms[tid]-m2) + ss[tid+off]*__expf(ms[tid+off]-m2);
      ms[tid] = m2;
    }
    __syncthreads();
  }
  float M = ms[0];
  float inv = 1.0f / ss[0];
  for (int i = tid; i < 8000; i += 256) {
    float4 v = p[i];
    v.x = __expf(v.x - M) * inv; v.y = __expf(v.y - M) * inv;
    v.z = __expf(v.z - M) * inv; v.w = __expf(v.w - M) * inv;
    p[i] = v;
  }
}

// ---------------- host ----------------

extern "C" void kernel_launch(void* const* d_in, const int* in_sizes, int n_in,
                              void* d_out, int out_size, void* d_ws, size_t ws_size,
                              hipStream_t stream){
  const float* yts   = (const float*)d_in[0];
  const float* enc_h = (const float*)d_in[1];
  const int*   tgt   = (const int*)d_in[2];
  const float* emb   = (const float*)d_in[3];
  const float* ayi_w = (const float*)d_in[6];
  const float* aw_w  = (const float*)d_in[8];
  const float* wf_w = (const float*)d_in[10]; const float* wf_b = (const float*)d_in[11];
  const float* uf_w = (const float*)d_in[12]; const float* uf_b = (const float*)d_in[13];
  const float* wi_w = (const float*)d_in[14]; const float* wi_b = (const float*)d_in[15];
  const float* ui_w = (const float*)d_in[16]; const float* ui_b = (const float*)d_in[17];
  const float* wo_w = (const float*)d_in[18]; const float* wo_b = (const float*)d_in[19];
  const float* uo_w = (const float*)d_in[20]; const float* uo_b = (const float*)d_in[21];
  const float* wc_w = (const float*)d_in[22]; const float* wc_b = (const float*)d_in[23];
  const float* uc_w = (const float*)d_in[24]; const float* uc_b = (const float*)d_in[25];
  const float* xh_w = (const float*)d_in[26]; const float* xh_b = (const float*)d_in[27];
  const float* cls_w= (const float*)d_in[28]; const float* cls_b= (const float*)d_in[29];

  float* out = (float*)d_out;
  float* outAttn = out + (size_t)B_ * T_ * V_;

  char* wsb = (char*)d_ws;
  size_t off = 0;
  auto alloc = [&](size_t bytes)->char*{
    char* p = wsb + off; off += (bytes + 255) & ~(size_t)255; return p;
  };
  ushort* clsT  = (ushort*)alloc((size_t)V_ * 1024 * 2);     // 65.5 MB
  ushort* xhT   = (ushort*)alloc((size_t)1024 * 1024 * 2);   // 2 MB
  ushort* WcatT = (ushort*)alloc((size_t)4096 * 1024 * 2);   // 8 MB
  ushort* UcatT = (ushort*)alloc((size_t)4096 * 1024 * 2);   // 8 MB
  float*  biasU = (float*)alloc(4096 * 4);
  float*  vvec  = (float*)alloc(S_ * 4);
  float*  scores= (float*)alloc(B_ * SE_ * 4);
  float*  attnw = (float*)alloc(B_ * SE_ * 4);
  float*  ctx   = (float*)alloc(B_ * S_ * 4);
  ushort* Xb    = (ushort*)alloc((size_t)4096 * 1024 * 2);   // 8 MB (aliased as Zb later)
  ushort* preb  = (ushort*)alloc((size_t)4096 * 4096 * 2);   // 33.6 MB
  ushort* Hst   = (ushort*)alloc((size_t)65 * 64 * 1024 * 2);// 8.5 MB
  if (off > ws_size) return;
  ushort* Zb = Xb; // Xb dead after pre-GEMM; reuse for Z

  dim3 tb(32, 8);
  // weight conversions (independent)
  k_transcvt<<<dim3(V_/32, 32), tb, 0, stream>>>(cls_w, clsT, 1024, V_);
  k_transcvt<<<dim3(32, 32), tb, 0, stream>>>(xh_w, xhT, 1024, 1024);
  k_transcvt<<<dim3(32, 32), tb, 0, stream>>>(wf_w, WcatT + 0u*1048576u, 1024, 1024);
  k_transcvt<<<dim3(32, 32), tb, 0, stream>>>(wi_w, WcatT + 1u*1048576u, 1024, 1024);
  k_transcvt<<<dim3(32, 32), tb, 0, stream>>>(wo_w, WcatT + 2u*1048576u, 1024, 1024);
  k_transcvt<<<dim3(32, 32), tb, 0, stream>>>(wc_w, WcatT + 3u*1048576u, 1024, 1024);
  k_transcvt<<<dim3(32, 32), tb, 0, stream>>>(uf_w, UcatT + 0u*1048576u, 1024, 1024);
  k_transcvt<<<dim3(32, 32), tb, 0, stream>>>(ui_w, UcatT + 1u*1048576u, 1024, 1024);
  k_transcvt<<<dim3(32, 32), tb, 0, stream>>>(uo_w, UcatT + 2u*1048576u, 1024, 1024);
  k_transcvt<<<dim3(32, 32), tb, 0, stream>>>(uc_w, UcatT + 3u*1048576u, 1024, 1024);
  k_packbias<<<16, 256, 0, stream>>>(wf_b, wi_b, wo_b, wc_b, uf_b, ui_b, uo_b, uc_b, biasU);
  k_cvt<<<64, 256, 0, stream>>>(enc_h, Hst, 16384);
  k_gathercvt<<<4096, 256, 0, stream>>>(emb, tgt, Xb);

  // attention (state-independent)
  k_attnvec<<<256, 256, 0, stream>>>(ayi_w, aw_w, vvec);
  k_scores<<<2048, 256, 0, stream>>>(yts, vvec, scores);
  k_attn<<<64, 128, 0, stream>>>(scores, attnw, outAttn);
  k_ctx<<<256, 256, 0, stream>>>(yts, attnw, ctx);

  // pre = X @ Ucat + biasU  -> bf16 [4096][4096]
  k_mfma_gemm<2><<<dim3(32, 32), 256, 0, stream>>>(Xb, UcatT, biasU, preb, 4096, 4096);

  // sequential recurrence
  for (int t = 0; t < T_; ++t) {
    k_step<<<16, 256, 0, stream>>>(Hst + (size_t)t * 65536, WcatT,
                                   preb + (size_t)t * 262144, ctx,
                                   Hst + (size_t)(t+1) * 65536);
  }

  // Z = H @ xh_w + xh_b  -> bf16 [4096][1024]
  k_mfma_gemm<2><<<dim3(8, 32), 256, 0, stream>>>(Hst + 65536, xhT, xh_b, Zb, 4096, 1024);
  // out = Z @ cls_w + cls_b (rows remapped t*64+b -> b*64+t), f32
  k_mfma_gemm<1><<<dim3(V_/128, 32), 256, 0, stream>>>(Zb, clsT, cls_b, out, 4096, V_);
  // softmax rows in place
  k_softmaxV<<<4096, 256, 0, stream>>>(out);
}